// Round 3
// baseline (1314.677 us; speedup 1.0000x reference)
//
#include <hip/hip_runtime.h>

// 2-layer LSTM (H=32, D=10, T=512), layer-pipelined, packed-fp32 edition.
// threads   0..127: layer-1 gate for timestep k
// threads 128..255: layer-2 gate for timestep k-1 (software wavefront)
// Weights live in NAMED float2 scalars (SSA -> cannot be invalidated by the
// memory clobber / barrier, compiler must keep in VGPRs or visibly spill).
// Dot products written as float2 lane-pairs to trigger v_pk_fma_f32.

#define HH 32
#define DD 10
#define TT 512

typedef __attribute__((ext_vector_type(2))) float f2;
typedef __attribute__((ext_vector_type(4))) float f4;

__device__ __forceinline__ f2 pkfma(f2 a, f2 b, f2 c) {
    f2 r;
    r.x = fmaf(a.x, b.x, c.x);
    r.y = fmaf(a.y, b.y, c.y);
    return r;
}
__device__ __forceinline__ f2 lo2(f4 v) { return __builtin_shufflevector(v, v, 0, 1); }
__device__ __forceinline__ f2 hi2(f4 v) { return __builtin_shufflevector(v, v, 2, 3); }

__device__ __forceinline__ float fast_sigmoid(float v) {
    float e = __expf(-v);
    return __builtin_amdgcn_rcpf(1.0f + e);
}
__device__ __forceinline__ float fast_tanh(float v) {
    return fmaf(2.0f, fast_sigmoid(2.0f * v), -1.0f);
}

#define DECL16(W) f2 W##0,W##1,W##2,W##3,W##4,W##5,W##6,W##7, \
                     W##8,W##9,W##10,W##11,W##12,W##13,W##14,W##15;
#define LDW16(W, P) do { \
    W##0 =(P)[0];  W##1 =(P)[1];  W##2 =(P)[2];  W##3 =(P)[3];  \
    W##4 =(P)[4];  W##5 =(P)[5];  W##6 =(P)[6];  W##7 =(P)[7];  \
    W##8 =(P)[8];  W##9 =(P)[9];  W##10=(P)[10]; W##11=(P)[11]; \
    W##12=(P)[12]; W##13=(P)[13]; W##14=(P)[14]; W##15=(P)[15]; \
} while (0)
#define DOT16(W, P) do { \
    f4 _v0=(P)[0], _v1=(P)[1], _v2=(P)[2], _v3=(P)[3]; \
    f4 _v4=(P)[4], _v5=(P)[5], _v6=(P)[6], _v7=(P)[7]; \
    aa = pkfma(W##0 , lo2(_v0), aa); ab = pkfma(W##1 , hi2(_v0), ab); \
    aa = pkfma(W##2 , lo2(_v1), aa); ab = pkfma(W##3 , hi2(_v1), ab); \
    aa = pkfma(W##4 , lo2(_v2), aa); ab = pkfma(W##5 , hi2(_v2), ab); \
    aa = pkfma(W##6 , lo2(_v3), aa); ab = pkfma(W##7 , hi2(_v3), ab); \
    aa = pkfma(W##8 , lo2(_v4), aa); ab = pkfma(W##9 , hi2(_v4), ab); \
    aa = pkfma(W##10, lo2(_v5), aa); ab = pkfma(W##11, hi2(_v5), ab); \
    aa = pkfma(W##12, lo2(_v6), aa); ab = pkfma(W##13, hi2(_v6), ab); \
    aa = pkfma(W##14, lo2(_v7), aa); ab = pkfma(W##15, hi2(_v7), ab); \
} while (0)

__global__ __launch_bounds__(256, 4) void lstm2_pk(
    const float* __restrict__ x,
    const float* __restrict__ Wih0, const float* __restrict__ Whh0,
    const float* __restrict__ bih0, const float* __restrict__ bhh0,
    const float* __restrict__ Wih1, const float* __restrict__ Whh1,
    const float* __restrict__ bih1, const float* __restrict__ bhh1,
    const float* __restrict__ Wfc,  const float* __restrict__ bfc,
    float* __restrict__ out)
{
    __shared__ __align__(16) float xs[TT * DD];     // 20480 B
    __shared__ __align__(16) float h1buf[2][HH];
    __shared__ __align__(16) float h2buf[2][HH];
    __shared__ __align__(16) float gl[256];

    const int tid  = threadIdx.x;
    const bool isL1 = tid < 128;
    const int tl   = tid & 127;
    const int j    = tl >> 2;          // hidden unit
    const int q    = tl & 3;           // 0=i 1=f 2=g(tanh) 3=o
    const int row  = q * HH + j;

    // ---- stage this batch's x into LDS ----
    {
        const float4* src = (const float4*)(x + (size_t)blockIdx.x * TT * DD);
        float4* dst = (float4*)xs;
        #pragma unroll
        for (int i = 0; i < 5; i++) dst[tid + 256 * i] = src[tid + 256 * i];
    }

    // ---- named-scalar weights (forced SSA) ----
    DECL16(WH)   // multiplies h1(prev) in both roles
    DECL16(WA)   // L1: x weights (first 5 used); L2: h2-recurrent weights
    float bb;
    if (isL1) {
        const f2* wh = (const f2*)(Whh0 + row * HH);
        LDW16(WH, wh);
        const f2* wx = (const f2*)(Wih0 + row * DD);
        WA0 = wx[0]; WA1 = wx[1]; WA2 = wx[2]; WA3 = wx[3]; WA4 = wx[4];
        WA5=WA6=WA7=WA8=WA9=WA10=WA11=WA12=WA13=WA14=WA15=(f2)(0.0f);
        bb = bih0[row] + bhh0[row];
    } else {
        const f2* wh = (const f2*)(Wih1 + row * HH);   // multiplies h1 input
        LDW16(WH, wh);
        const f2* wa = (const f2*)(Whh1 + row * HH);   // multiplies h2 recur
        LDW16(WA, wa);
        bb = bih1[row] + bhh1[row];
    }

    // activation: act(v) = sB * sigmoid(sA*v) + sC   (tanh when q==2)
    const bool is_t = (q == 2);
    const float sA = is_t ? 2.0f : 1.0f;
    const float sB = is_t ? 2.0f : 1.0f;
    const float sC = is_t ? -1.0f : 0.0f;

    // h-write targets per parity (precomputed, branch-free in loop)
    float* hw0; float* hw1;
    if (isL1) { hw0 = &h1buf[0][j]; hw1 = &h1buf[1][j]; }   // h1(k) @ parity k&1
    else      { hw0 = &h2buf[1][j]; hw1 = &h2buf[0][j]; }   // h2(k-1) @ parity (k-1)&1

    if (tid < 64)       (&h1buf[0][0])[tid]      = 0.0f;
    else if (tid < 128) (&h2buf[0][0])[tid - 64] = 0.0f;

    float c = 0.0f;
    __syncthreads();

    for (int k = 0; k <= TT; ++k) {
        const int pr = k & 1;
        const bool active = isL1 ? (k < TT) : (k > 0);
        float a;
        if (active) {
            f2 aa = {bb, 0.0f};
            f2 ab = {0.0f, 0.0f};
            if (isL1) {
                const f2* xp = (const f2*)&xs[k * DD];      // 8B aligned
                f2 X0=xp[0], X1=xp[1], X2=xp[2], X3=xp[3], X4=xp[4];
                aa = pkfma(WA0, X0, aa); ab = pkfma(WA1, X1, ab);
                aa = pkfma(WA2, X2, aa); ab = pkfma(WA3, X3, ab);
                aa = pkfma(WA4, X4, aa);
            } else {
                const f4* h2p = (const f4*)&h2buf[pr][0];   // h2(k-2)
                DOT16(WA, h2p);
            }
            const f4* h1p = (const f4*)&h1buf[pr ^ 1][0];   // h1(k-1)
            DOT16(WH, h1p);
            float s = (aa.x + aa.y) + (ab.x + ab.y);
            a = fmaf(sB, fast_sigmoid(sA * s), sC);
        }

        if (active) {
            gl[tid] = a;
            asm volatile("" ::: "memory");   // order intra-wave LDS write->read
            f4 gv = *(const f4*)&gl[tid & ~3];              // i, f, g~, o
            c = fmaf(gv.y, c, gv.x * gv.z);
            float h = gv.w * fast_tanh(c);
            if (q == 0) *(pr ? hw1 : hw0) = h;
        }
        __syncthreads();
    }

    // ---- final FC on h2(T-1) (parity 1) ----
    if (tid == 0) {
        float v = bfc[0];
        #pragma unroll
        for (int m = 0; m < HH; ++m) v = fmaf(h2buf[1][m], Wfc[m], v);
        out[blockIdx.x] = v;
    }
}

extern "C" void kernel_launch(void* const* d_in, const int* in_sizes, int n_in,
                              void* d_out, int out_size, void* d_ws, size_t ws_size,
                              hipStream_t stream) {
    const float* x    = (const float*)d_in[0];
    const float* Wih0 = (const float*)d_in[1];
    const float* Whh0 = (const float*)d_in[2];
    const float* bih0 = (const float*)d_in[3];
    const float* bhh0 = (const float*)d_in[4];
    const float* Wih1 = (const float*)d_in[5];
    const float* Whh1 = (const float*)d_in[6];
    const float* bih1 = (const float*)d_in[7];
    const float* bhh1 = (const float*)d_in[8];
    const float* Wfc  = (const float*)d_in[9];
    const float* bfc  = (const float*)d_in[10];
    float* out = (float*)d_out;

    const int B = in_sizes[0] / (TT * DD);   // 4096
    dim3 grid(B), block(256);
    hipLaunchKernelGGL(lstm2_pk, grid, block, 0, stream,
                       x, Wih0, Whh0, bih0, bhh0,
                       Wih1, Whh1, bih1, bhh1, Wfc, bfc, out);
}